// Round 1
// baseline (5668.309 us; speedup 1.0000x reference)
//
#include <hip/hip_runtime.h>
#include <cstdint>
#include <cstddef>

// ---------------------------------------------------------------------------
// MMPrompt pipeline, round 1: pure f32, correctness-first.
// All large intermediates live in d_out (302 MB) via phased overlays; only p2
// (input of the final GEMM that overwrites d_out) lives in d_ws.
// ---------------------------------------------------------------------------

namespace {

constexpr int NE   = 30000;   // entities
constexpr int NM   = 6000;    // movies
constexpr int Dm   = 384;     // entity hidden
constexpr int Hm   = 768;     // hidden
constexpr int NREL = 12;
constexpr int EKG  = 200000;
constexpr int EC   = 200000;
constexpr int ES   = 80000;
constexpr int Bc   = 16;
constexpr int LE   = 48;
constexpr int LT   = 256;
constexpr int NTOK = Bc * LT;     // 4096
constexpr int NO   = 18432;       // n_layer*n_block*H

constexpr size_t NBf = (size_t)NE * Dm;   // 11,520,000
constexpr size_t MBF = (size_t)NM * Dm;   // 2,304,000

// ---- phase 1 overlay (graph work) ----
constexpr size_t OFF_AGG  = 0;                 // 46 MB, also cprev (c1,c3)
constexpr size_t OFF_ENT0 = NBf;
constexpr size_t OFF_ACC  = 2 * NBf;
constexpr size_t OFF_CCUR = 3 * NBf;
constexpr size_t OFF_NF   = 4 * NBf;
constexpr size_t OFF_G1   = OFF_NF + MBF;
constexpr size_t OFF_G2   = OFF_G1 + MBF;
constexpr size_t OFF_MM   = OFF_G2 + MBF;
constexpr size_t OFF_CNT  = OFF_MM + MBF;                  // 12*30000 f32
constexpr size_t OFF_WCAT = OFF_CNT + (size_t)NREL * NE;   // 12*384*384
constexpr size_t OFF_ENT  = OFF_WCAT + (size_t)NREL * Dm * Dm; // 57,425,472
constexpr size_t OFF_EEMB = OFF_ENT + NBf;                 // 768*768
constexpr size_t OFF_DISC = OFF_EEMB + (size_t)Bc * LE * Hm;
constexpr size_t OFF_DIST = OFF_DISC + NE;
constexpr size_t OFF_DISI = OFF_DIST + NM;
constexpr size_t OFF_END  = OFF_DISI + NM;                 // 69,577,296

// ---- phase 2 overlay (MLP/token work; earlier graph buffers are dead) ----
constexpr size_t OFF_HID  = 0;                          // 30000*192
constexpr size_t OFF_ENT2 = (size_t)NE * 192;
constexpr size_t OFF_E768 = OFF_ENT2 + NBf;             // 30000*768
constexpr size_t OFF_THID = OFF_E768 + (size_t)NE * Hm; // 40,320,000
constexpr size_t OFF_TOK  = OFF_THID + (size_t)NTOK * Dm;
constexpr size_t OFF_TOK2 = OFF_TOK + (size_t)NTOK * Hm;
constexpr size_t OFF_Q    = OFF_TOK2 + (size_t)NTOK * Hm;
constexpr size_t OFF_PR0  = OFF_Q + (size_t)NTOK * Hm;
constexpr size_t OFF_PHID = OFF_PR0 + (size_t)NTOK * Hm;
constexpr size_t OFF_P2E  = OFF_PHID + (size_t)NTOK * Dm; // 56,048,640

static_assert(OFF_END <= 75497472ull, "d_out overlay overflow");
static_assert(OFF_P2E <= OFF_ENT, "phase2 overlay collides with ENT");

inline int cdiv(long a, long b) { return (int)((a + b - 1) / b); }

} // namespace

// ---------------------------------------------------------------------------
// small kernels
// ---------------------------------------------------------------------------

__global__ void k_count_type(const int* __restrict__ dst, const int* __restrict__ typ,
                             float* __restrict__ cnt, int E) {
  int i = blockIdx.x * 256 + threadIdx.x;
  if (i < E) atomicAdd(&cnt[(size_t)typ[i] * NE + dst[i]], 1.0f);
}

__global__ void k_deg(const int* __restrict__ dst, float* __restrict__ deg, int E) {
  int i = blockIdx.x * 256 + threadIdx.x;
  if (i < E) atomicAdd(&deg[dst[i]], 1.0f);
}

__global__ void k_dis(float* __restrict__ d, int n) {
  int i = blockIdx.x * 256 + threadIdx.x;
  if (i < n) d[i] = rsqrtf(d[i] + 1.0f);   // deg includes +1 self loop
}

__global__ void k_wcat(const float* __restrict__ comp, const float* __restrict__ bases,
                       float* __restrict__ Wc) {
  int idx = blockIdx.x * 256 + threadIdx.x;
  if (idx >= NREL * Dm * Dm) return;
  int r = idx / (Dm * Dm);
  int io = idx - r * (Dm * Dm);
  float s = 0.f;
#pragma unroll
  for (int b = 0; b < 8; ++b) s += comp[r * 8 + b] * bases[(size_t)b * Dm * Dm + io];
  Wc[idx] = s;
}

// wave per edge: agg[dst] += (1/cnt_r[dst]) * x[src] for edges of type r
__global__ void k_scatter_rgcn(const int* __restrict__ ei, const int* __restrict__ typ,
                               const float* __restrict__ cnt, const float* __restrict__ x,
                               float* __restrict__ agg, int E, int r) {
  int w = (int)((blockIdx.x * (size_t)blockDim.x + threadIdx.x) >> 6);
  int lane = threadIdx.x & 63;
  if (w >= E) return;
  if (typ[w] != r) return;
  int s = ei[w], d = ei[E + w];
  float c = 1.0f / cnt[(size_t)r * NE + d];
  const float* xs = x + (size_t)s * Dm;
  float* od = agg + (size_t)d * Dm;
#pragma unroll
  for (int i = 0; i < Dm / 64; ++i)
    atomicAdd(&od[lane + 64 * i], c * xs[lane + 64 * i]);
}

__global__ void k_gcn_init(const float* __restrict__ x, const float* __restrict__ dis,
                           float* __restrict__ out, int n) {
  size_t i = (size_t)blockIdx.x * 256 + threadIdx.x;
  if (i >= (size_t)n * Dm) return;
  int row = (int)(i / Dm);
  float d = dis[row];
  out[i] = d * d * x[i];   // self-loop term
}

__global__ void k_gcn_scatter(const int* __restrict__ ei, const float* __restrict__ dis,
                              const float* __restrict__ x, float* __restrict__ out, int E) {
  int w = (int)((blockIdx.x * (size_t)blockDim.x + threadIdx.x) >> 6);
  int lane = threadIdx.x & 63;
  if (w >= E) return;
  int s = ei[w], d = ei[E + w];
  float c = dis[s] * dis[d];
  const float* xs = x + (size_t)s * Dm;
  float* od = out + (size_t)d * Dm;
#pragma unroll
  for (int i = 0; i < Dm / 64; ++i)
    atomicAdd(&od[lane + 64 * i], c * xs[lane + 64 * i]);
}

__global__ void k_copy(float* __restrict__ d, const float* __restrict__ s, size_t n) {
  size_t i = (size_t)blockIdx.x * 256 + threadIdx.x;
  if (i < n) d[i] = s[i];
}

__global__ void k_addto(float* __restrict__ d, const float* __restrict__ s, size_t n) {
  size_t i = (size_t)blockIdx.x * 256 + threadIdx.x;
  if (i < n) d[i] += s[i];
}

__global__ void k_scale_from(float* __restrict__ d, const float* __restrict__ s,
                             float a, size_t n) {
  size_t i = (size_t)blockIdx.x * 256 + threadIdx.x;
  if (i < n) d[i] = a * s[i];
}

__global__ void k_gather(const int* __restrict__ idx, const float* __restrict__ x,
                         float* __restrict__ out, int rows, int D) {
  size_t i = (size_t)blockIdx.x * 256 + threadIdx.x;
  if (i >= (size_t)rows * D) return;
  int r = (int)(i / D);
  int d = (int)(i - (size_t)r * D);
  out[i] = x[(size_t)idx[r] * D + d];
}

__global__ void k_scatter_movie(const int* __restrict__ mte, const float* __restrict__ mm,
                                float* __restrict__ ent) {
  size_t i = (size_t)blockIdx.x * 256 + threadIdx.x;
  if (i >= MBF) return;
  int m = (int)(i / Dm);
  int d = (int)(i - (size_t)m * Dm);
  atomicAdd(&ent[(size_t)mte[m] * Dm + d], 0.25f * mm[i]);
}

// ---------------------------------------------------------------------------
// f32 GEMM: C = act(A[M,K] @ W[K,N] + bias (+ res)), or C += A@W (ACCUM).
// 128x64 tile, BK=16, 256 threads, 8x4 per thread. Requires N%64==0, K%16==0.
// ---------------------------------------------------------------------------
template <bool RELU, bool ACCUM, bool RES>
__global__ __launch_bounds__(256) void gemm128(
    const float* __restrict__ A, const float* __restrict__ W,
    const float* __restrict__ bias, const float* __restrict__ Rp,
    float* __restrict__ C, int M, int N, int K) {
  __shared__ float As[16][132];
  __shared__ float Ws[16][64];
  const int tid = threadIdx.x;
  const int tx = tid & 15;
  const int ty = tid >> 4;
  const int bm = blockIdx.x * 128, bn = blockIdx.y * 64;
  float acc[8][4] = {};
  const int arow = tid >> 1;         // 0..127
  const int acol = (tid & 1) * 8;    // 0 or 8
  const bool aval = (bm + arow) < M;
  const float* Ap = A + (size_t)(bm + arow) * K + acol;
  const int wrow = tid >> 4;         // 0..15
  const int wcol = (tid & 15) * 4;   // 0..60
  const float* Wp = W + (size_t)wrow * N + bn + wcol;

  for (int k0 = 0; k0 < K; k0 += 16) {
    float4 a0 = {0.f, 0.f, 0.f, 0.f}, a1 = {0.f, 0.f, 0.f, 0.f};
    if (aval) {
      a0 = *(const float4*)(Ap + k0);
      a1 = *(const float4*)(Ap + k0 + 4);
    }
    float4 wv = *(const float4*)(Wp + (size_t)k0 * N);
    __syncthreads();
    As[acol + 0][arow] = a0.x; As[acol + 1][arow] = a0.y;
    As[acol + 2][arow] = a0.z; As[acol + 3][arow] = a0.w;
    As[acol + 4][arow] = a1.x; As[acol + 5][arow] = a1.y;
    As[acol + 6][arow] = a1.z; As[acol + 7][arow] = a1.w;
    *(float4*)&Ws[wrow][wcol] = wv;
    __syncthreads();
#pragma unroll
    for (int k = 0; k < 16; ++k) {
      float4 av0 = *(const float4*)&As[k][ty * 8];
      float4 av1 = *(const float4*)&As[k][ty * 8 + 4];
      float4 bv = *(const float4*)&Ws[k][tx * 4];
      float ar[8] = {av0.x, av0.y, av0.z, av0.w, av1.x, av1.y, av1.z, av1.w};
      float br[4] = {bv.x, bv.y, bv.z, bv.w};
#pragma unroll
      for (int i = 0; i < 8; ++i)
#pragma unroll
        for (int j = 0; j < 4; ++j)
          acc[i][j] = fmaf(ar[i], br[j], acc[i][j]);
    }
  }
#pragma unroll
  for (int i = 0; i < 8; ++i) {
    int r = bm + ty * 8 + i;
    if (r >= M) continue;
#pragma unroll
    for (int j = 0; j < 4; ++j) {
      int c = bn + tx * 4 + j;
      float v = acc[i][j];
      if (bias) v += bias[c];
      if (RES) v += Rp[(size_t)r * N + c];
      if (RELU) v = fmaxf(v, 0.f);
      if (ACCUM) C[(size_t)r * N + c] += v;
      else C[(size_t)r * N + c] = v;
    }
  }
}

// final GEMM: out = p2 @ pp2_w + pp2_b, written transposed to
// [n_layer, n_block, B, n_head, LT, head_dim]
__global__ __launch_bounds__(256) void gemm_final(
    const float* __restrict__ A, const float* __restrict__ W,
    const float* __restrict__ bias, float* __restrict__ O,
    int M, int N, int K) {
  __shared__ float As[16][132];
  __shared__ float Ws[16][64];
  const int tid = threadIdx.x;
  const int tx = tid & 15;
  const int ty = tid >> 4;
  const int bm = blockIdx.x * 128, bn = blockIdx.y * 64;
  float acc[8][4] = {};
  const int arow = tid >> 1;
  const int acol = (tid & 1) * 8;
  const bool aval = (bm + arow) < M;
  const float* Ap = A + (size_t)(bm + arow) * K + acol;
  const int wrow = tid >> 4;
  const int wcol = (tid & 15) * 4;
  const float* Wp = W + (size_t)wrow * N + bn + wcol;

  for (int k0 = 0; k0 < K; k0 += 16) {
    float4 a0 = {0.f, 0.f, 0.f, 0.f}, a1 = {0.f, 0.f, 0.f, 0.f};
    if (aval) {
      a0 = *(const float4*)(Ap + k0);
      a1 = *(const float4*)(Ap + k0 + 4);
    }
    float4 wv = *(const float4*)(Wp + (size_t)k0 * N);
    __syncthreads();
    As[acol + 0][arow] = a0.x; As[acol + 1][arow] = a0.y;
    As[acol + 2][arow] = a0.z; As[acol + 3][arow] = a0.w;
    As[acol + 4][arow] = a1.x; As[acol + 5][arow] = a1.y;
    As[acol + 6][arow] = a1.z; As[acol + 7][arow] = a1.w;
    *(float4*)&Ws[wrow][wcol] = wv;
    __syncthreads();
#pragma unroll
    for (int k = 0; k < 16; ++k) {
      float4 av0 = *(const float4*)&As[k][ty * 8];
      float4 av1 = *(const float4*)&As[k][ty * 8 + 4];
      float4 bv = *(const float4*)&Ws[k][tx * 4];
      float ar[8] = {av0.x, av0.y, av0.z, av0.w, av1.x, av1.y, av1.z, av1.w};
      float br[4] = {bv.x, bv.y, bv.z, bv.w};
#pragma unroll
      for (int i = 0; i < 8; ++i)
#pragma unroll
        for (int j = 0; j < 4; ++j)
          acc[i][j] = fmaf(ar[i], br[j], acc[i][j]);
    }
  }
#pragma unroll
  for (int i = 0; i < 8; ++i) {
    int r = bm + ty * 8 + i;
    if (r >= M) continue;
    int b = r >> 8;        // row = b*256 + t
    int t = r & 255;
#pragma unroll
    for (int j = 0; j < 4; ++j) {
      int c = bn + tx * 4 + j;
      float v = acc[i][j] + bias[c];
      int l = c / 1536;
      int rem = c - l * 1536;
      int blk = rem / 768;
      int rem2 = rem - blk * 768;
      int hh = rem2 >> 6;
      int dd = rem2 & 63;
      size_t oi = (((((size_t)l * 2 + blk) * 16 + b) * 12 + hh) * 256 + t) * 64 + dd;
      O[oi] = v;
    }
  }
}

// fused cross-attention: one wave per (b,t)
__global__ __launch_bounds__(256) void k_attn(const float* __restrict__ q,
                                              const float* __restrict__ eemb,
                                              const float* __restrict__ tok,
                                              float* __restrict__ out) {
  int gw = (int)((blockIdx.x * (size_t)blockDim.x + threadIdx.x) >> 6);
  int lane = threadIdx.x & 63;
  if (gw >= NTOK) return;
  int b = gw >> 8;
  const float* qr = q + (size_t)gw * Hm;
  float qreg[12];
#pragma unroll
  for (int i = 0; i < 12; ++i) qreg[i] = qr[lane + 64 * i];
  const float* eb = eemb + (size_t)b * LE * Hm;
  float myA = -3.0e38f;   // lane e (<48) holds score e
  for (int e = 0; e < LE; ++e) {
    const float* er = eb + (size_t)e * Hm;
    float s = 0.f;
#pragma unroll
    for (int i = 0; i < 12; ++i) s = fmaf(qreg[i], er[lane + 64 * i], s);
#pragma unroll
    for (int off = 32; off > 0; off >>= 1) s += __shfl_xor(s, off);
    if (lane == e) myA = s * (1.0f / 768.0f);
  }
  float mx = myA;
#pragma unroll
  for (int off = 32; off > 0; off >>= 1) mx = fmaxf(mx, __shfl_xor(mx, off));
  float p = (lane < LE) ? expf(myA - mx) : 0.f;
  float sum = p;
#pragma unroll
  for (int off = 32; off > 0; off >>= 1) sum += __shfl_xor(sum, off);
  float w = p / sum;
  const float* tr = tok + (size_t)gw * Hm;
  float acc[12];
#pragma unroll
  for (int i = 0; i < 12; ++i) acc[i] = tr[lane + 64 * i];
  for (int e = 0; e < LE; ++e) {
    float we = __shfl(w, e);
    const float* er = eb + (size_t)e * Hm;
#pragma unroll
    for (int i = 0; i < 12; ++i) acc[i] = fmaf(we, er[lane + 64 * i], acc[i]);
  }
  float* orow = out + (size_t)gw * Hm;
#pragma unroll
  for (int i = 0; i < 12; ++i) orow[lane + 64 * i] = acc[i];
}

// ---------------------------------------------------------------------------

extern "C" void kernel_launch(void* const* d_in, const int* in_sizes, int n_in,
                              void* d_out, int out_size, void* d_ws, size_t ws_size,
                              hipStream_t stream) {
  (void)in_sizes; (void)n_in; (void)out_size; (void)ws_size;

  const float* x_node = (const float*)d_in[0];
  const float* bases  = (const float*)d_in[1];
  const float* comp   = (const float*)d_in[2];
  const float* root   = (const float*)d_in[3];
  const float* rbias  = (const float*)d_in[4];
  const float* ep1w1  = (const float*)d_in[5];
  const float* ep1b1  = (const float*)d_in[6];
  const float* ep1w2  = (const float*)d_in[7];
  const float* ep1b2  = (const float*)d_in[8];
  const float* ep2w   = (const float*)d_in[9];
  const float* ep2b   = (const float*)d_in[10];
  const float* tp1w1  = (const float*)d_in[11];
  const float* tp1b1  = (const float*)d_in[12];
  const float* tp1w2  = (const float*)d_in[13];
  const float* tp1b2  = (const float*)d_in[14];
  const float* tp2w   = (const float*)d_in[15];
  const float* tp2b   = (const float*)d_in[16];
  const float* caw    = (const float*)d_in[17];
  const float* pp1w1  = (const float*)d_in[18];
  const float* pp1b1  = (const float*)d_in[19];
  const float* pp1w2  = (const float*)d_in[20];
  const float* pp1b2  = (const float*)d_in[21];
  const float* pp2w   = (const float*)d_in[22];
  const float* pp2b   = (const float*)d_in[23];
  const float* tokens = (const float*)d_in[24];
  const int* ei_kg = (const int*)d_in[25];
  const int* etype = (const int*)d_in[26];
  const int* ei_c  = (const int*)d_in[27];
  const int* ei_ts = (const int*)d_in[28];
  const int* ei_is = (const int*)d_in[29];
  const int* mte   = (const int*)d_in[30];
  const int* eids  = (const int*)d_in[31];

  float* O = (float*)d_out;
  float* f_agg  = O + OFF_AGG;
  float* f_ent0 = O + OFF_ENT0;
  float* f_acc  = O + OFF_ACC;
  float* f_ccur = O + OFF_CCUR;
  float* f_nf   = O + OFF_NF;
  float* f_g1   = O + OFF_G1;
  float* f_g2   = O + OFF_G2;
  float* f_mm   = O + OFF_MM;
  float* f_cnt  = O + OFF_CNT;
  float* f_wcat = O + OFF_WCAT;
  float* f_ent  = O + OFF_ENT;
  float* f_eemb = O + OFF_EEMB;
  float* f_disc = O + OFF_DISC;
  float* f_dist = O + OFF_DIST;
  float* f_disi = O + OFF_DISI;
  float* f_hid  = O + OFF_HID;
  float* f_ent2 = O + OFF_ENT2;
  float* f_e768 = O + OFF_E768;
  float* f_thid = O + OFF_THID;
  float* f_tok  = O + OFF_TOK;
  float* f_tok2 = O + OFF_TOK2;
  float* f_q    = O + OFF_Q;
  float* f_pr0  = O + OFF_PR0;
  float* f_phid = O + OFF_PHID;
  float* f_p2   = (float*)d_ws;   // 4096*768 f32 = 12.6 MB — must NOT be in d_out

  const int EW = 256;  // elementwise block

  // ---------------- RGCN ----------------
  hipMemsetAsync(f_cnt, 0, (size_t)NREL * NE * 4, stream);
  k_count_type<<<cdiv(EKG, EW), EW, 0, stream>>>(ei_kg + EKG, etype, f_cnt, EKG);
  k_wcat<<<cdiv(NREL * Dm * Dm, EW), EW, 0, stream>>>(comp, bases, f_wcat);
  // out = x @ root + bias
  gemm128<false, false, false><<<dim3(cdiv(NE, 128), Dm / 64), 256, 0, stream>>>(
      x_node, root, rbias, nullptr, f_ent0, NE, Dm, Dm);
  for (int r = 0; r < NREL; ++r) {
    hipMemsetAsync(f_agg, 0, NBf * 4, stream);
    k_scatter_rgcn<<<cdiv((long)EKG * 64, EW), EW, 0, stream>>>(
        ei_kg, etype, f_cnt, x_node, f_agg, EKG, r);
    gemm128<false, true, false><<<dim3(cdiv(NE, 128), Dm / 64), 256, 0, stream>>>(
        f_agg, f_wcat + (size_t)r * Dm * Dm, nullptr, nullptr, f_ent0, NE, Dm, Dm);
  }
  k_addto<<<cdiv(NBf, EW), EW, 0, stream>>>(f_ent0, x_node, NBf);  // ent0 = rgcn + x

  // ---------------- degree norms ----------------
  hipMemsetAsync(f_disc, 0, NE * 4, stream);
  k_deg<<<cdiv(EC, EW), EW, 0, stream>>>(ei_c + EC, f_disc, EC);
  k_dis<<<cdiv(NE, EW), EW, 0, stream>>>(f_disc, NE);
  hipMemsetAsync(f_dist, 0, NM * 4, stream);
  k_deg<<<cdiv(ES, EW), EW, 0, stream>>>(ei_ts + ES, f_dist, ES);
  k_dis<<<cdiv(NM, EW), EW, 0, stream>>>(f_dist, NM);
  hipMemsetAsync(f_disi, 0, NM * 4, stream);
  k_deg<<<cdiv(ES, EW), EW, 0, stream>>>(ei_is + ES, f_disi, ES);
  k_dis<<<cdiv(NM, EW), EW, 0, stream>>>(f_disi, NM);

  // ---------------- movie branch ----------------
  k_gather<<<cdiv(MBF, EW), EW, 0, stream>>>(mte, f_ent0, f_nf, NM, Dm);
  hipMemsetAsync(f_mm, 0, MBF * 4, stream);
  // ts1
  k_gcn_init<<<cdiv(MBF, EW), EW, 0, stream>>>(f_nf, f_dist, f_g1, NM);
  k_gcn_scatter<<<cdiv((long)ES * 64, EW), EW, 0, stream>>>(ei_ts, f_dist, f_nf, f_g1, ES);
  k_addto<<<cdiv(MBF, EW), EW, 0, stream>>>(f_mm, f_g1, MBF);
  // ts2
  k_gcn_init<<<cdiv(MBF, EW), EW, 0, stream>>>(f_g1, f_dist, f_g2, NM);
  k_gcn_scatter<<<cdiv((long)ES * 64, EW), EW, 0, stream>>>(ei_ts, f_dist, f_g1, f_g2, ES);
  k_addto<<<cdiv(MBF, EW), EW, 0, stream>>>(f_mm, f_g2, MBF);
  // is1
  k_gcn_init<<<cdiv(MBF, EW), EW, 0, stream>>>(f_nf, f_disi, f_g1, NM);
  k_gcn_scatter<<<cdiv((long)ES * 64, EW), EW, 0, stream>>>(ei_is, f_disi, f_nf, f_g1, ES);
  k_addto<<<cdiv(MBF, EW), EW, 0, stream>>>(f_mm, f_g1, MBF);
  // is2
  k_gcn_init<<<cdiv(MBF, EW), EW, 0, stream>>>(f_g1, f_disi, f_g2, NM);
  k_gcn_scatter<<<cdiv((long)ES * 64, EW), EW, 0, stream>>>(ei_is, f_disi, f_g1, f_g2, ES);
  k_addto<<<cdiv(MBF, EW), EW, 0, stream>>>(f_mm, f_g2, MBF);
  // f_mm now holds ts1+ts2+is1+is2; mm = 0.25*f_mm applied at scatter

  // ---------------- entity GCN chain ----------------
  k_copy<<<cdiv(NBf, EW), EW, 0, stream>>>(f_acc, f_ent0, NBf);
  // c1 -> f_agg
  k_gcn_init<<<cdiv(NBf, EW), EW, 0, stream>>>(f_ent0, f_disc, f_agg, NE);
  k_gcn_scatter<<<cdiv((long)EC * 64, EW), EW, 0, stream>>>(ei_c, f_disc, f_ent0, f_agg, EC);
  k_addto<<<cdiv(NBf, EW), EW, 0, stream>>>(f_acc, f_agg, NBf);
  // c2 -> f_ccur
  k_gcn_init<<<cdiv(NBf, EW), EW, 0, stream>>>(f_agg, f_disc, f_ccur, NE);
  k_gcn_scatter<<<cdiv((long)EC * 64, EW), EW, 0, stream>>>(ei_c, f_disc, f_agg, f_ccur, EC);
  k_addto<<<cdiv(NBf, EW), EW, 0, stream>>>(f_acc, f_ccur, NBf);
  // c3 -> f_agg (c1 dead)
  k_gcn_init<<<cdiv(NBf, EW), EW, 0, stream>>>(f_ccur, f_disc, f_agg, NE);
  k_gcn_scatter<<<cdiv((long)EC * 64, EW), EW, 0, stream>>>(ei_c, f_disc, f_ccur, f_agg, EC);
  k_addto<<<cdiv(NBf, EW), EW, 0, stream>>>(f_acc, f_agg, NBf);
  // ent = 0.25*(ent0+c1+c2+c3); ent[mte] += 0.25*mm
  k_scale_from<<<cdiv(NBf, EW), EW, 0, stream>>>(f_ent, f_acc, 0.25f, NBf);
  k_scatter_movie<<<cdiv(MBF, EW), EW, 0, stream>>>(mte, f_mm, f_ent);

  // ---------------- entity MLP ----------------
  gemm128<true, false, false><<<dim3(cdiv(NE, 128), 192 / 64), 256, 0, stream>>>(
      f_ent, ep1w1, ep1b1, nullptr, f_hid, NE, 192, Dm);
  gemm128<false, false, true><<<dim3(cdiv(NE, 128), Dm / 64), 256, 0, stream>>>(
      f_hid, ep1w2, ep1b2, f_ent, f_ent2, NE, Dm, 192);
  gemm128<false, false, false><<<dim3(cdiv(NE, 128), Hm / 64), 256, 0, stream>>>(
      f_ent2, ep2w, ep2b, nullptr, f_e768, NE, Hm, Dm);

  // ---------------- token path ----------------
  gemm128<true, false, false><<<dim3(cdiv(NTOK, 128), Dm / 64), 256, 0, stream>>>(
      tokens, tp1w1, tp1b1, nullptr, f_thid, NTOK, Dm, Hm);
  gemm128<false, false, true><<<dim3(cdiv(NTOK, 128), Hm / 64), 256, 0, stream>>>(
      f_thid, tp1w2, tp1b2, tokens, f_tok, NTOK, Hm, Dm);
  gemm128<false, false, false><<<dim3(cdiv(NTOK, 128), Hm / 64), 256, 0, stream>>>(
      f_tok, tp2w, tp2b, nullptr, f_tok2, NTOK, Hm, Hm);
  gemm128<false, false, false><<<dim3(cdiv(NTOK, 128), Hm / 64), 256, 0, stream>>>(
      f_tok2, caw, nullptr, nullptr, f_q, NTOK, Hm, Hm);

  k_gather<<<cdiv((long)Bc * LE * Hm, EW), EW, 0, stream>>>(eids, f_e768, f_eemb, Bc * LE, Hm);
  k_attn<<<cdiv((long)NTOK * 64, 256), 256, 0, stream>>>(f_q, f_eemb, f_tok2, f_pr0);

  gemm128<true, false, false><<<dim3(cdiv(NTOK, 128), Dm / 64), 256, 0, stream>>>(
      f_pr0, pp1w1, pp1b1, nullptr, f_phid, NTOK, Dm, Hm);
  gemm128<false, false, true><<<dim3(cdiv(NTOK, 128), Hm / 64), 256, 0, stream>>>(
      f_phid, pp1w2, pp1b2, f_pr0, f_p2, NTOK, Hm, Dm);

  // ---------------- final GEMM + transpose (overwrites ALL of d_out) -------
  gemm_final<<<dim3(cdiv(NTOK, 128), NO / 64), 256, 0, stream>>>(
      f_p2, pp2w, pp2b, O, NTOK, NO, Hm);
}

// Round 2
// 3583.573 us; speedup vs baseline: 1.5817x; 1.5817x over previous
//
#include <hip/hip_runtime.h>
#include <cstdint>
#include <cstddef>

// ---------------------------------------------------------------------------
// MMPrompt pipeline, round 2: all GEMMs -> bf16 MFMA (f32 in/out, in-kernel
// conversion). Graph scatters and elementwise stay f32.
// ---------------------------------------------------------------------------

namespace {

constexpr int NE   = 30000;
constexpr int NM   = 6000;
constexpr int Dm   = 384;
constexpr int Hm   = 768;
constexpr int NREL = 12;
constexpr int EKG  = 200000;
constexpr int EC   = 200000;
constexpr int ES   = 80000;
constexpr int Bc   = 16;
constexpr int LE   = 48;
constexpr int LT   = 256;
constexpr int NTOK = Bc * LT;     // 4096
constexpr int NO   = 18432;

constexpr size_t NBf = (size_t)NE * Dm;   // 11,520,000
constexpr size_t MBF = (size_t)NM * Dm;   // 2,304,000

// ---- phase 1 overlay (graph work) ----
constexpr size_t OFF_AGG  = 0;
constexpr size_t OFF_ENT0 = NBf;
constexpr size_t OFF_ACC  = 2 * NBf;
constexpr size_t OFF_CCUR = 3 * NBf;
constexpr size_t OFF_NF   = 4 * NBf;
constexpr size_t OFF_G1   = OFF_NF + MBF;
constexpr size_t OFF_G2   = OFF_G1 + MBF;
constexpr size_t OFF_MM   = OFF_G2 + MBF;
constexpr size_t OFF_CNT  = OFF_MM + MBF;
constexpr size_t OFF_WCAT = OFF_CNT + (size_t)NREL * NE;
constexpr size_t OFF_ENT  = OFF_WCAT + (size_t)NREL * Dm * Dm;
constexpr size_t OFF_EEMB = OFF_ENT + NBf;
constexpr size_t OFF_DISC = OFF_EEMB + (size_t)Bc * LE * Hm;
constexpr size_t OFF_DIST = OFF_DISC + NE;
constexpr size_t OFF_DISI = OFF_DIST + NM;
constexpr size_t OFF_END  = OFF_DISI + NM;

// ---- phase 2 overlay ----
constexpr size_t OFF_HID  = 0;
constexpr size_t OFF_ENT2 = (size_t)NE * 192;
constexpr size_t OFF_E768 = OFF_ENT2 + NBf;
constexpr size_t OFF_THID = OFF_E768 + (size_t)NE * Hm;
constexpr size_t OFF_TOK  = OFF_THID + (size_t)NTOK * Dm;
constexpr size_t OFF_TOK2 = OFF_TOK + (size_t)NTOK * Hm;
constexpr size_t OFF_Q    = OFF_TOK2 + (size_t)NTOK * Hm;
constexpr size_t OFF_PR0  = OFF_Q + (size_t)NTOK * Hm;
constexpr size_t OFF_PHID = OFF_PR0 + (size_t)NTOK * Hm;
constexpr size_t OFF_P2E  = OFF_PHID + (size_t)NTOK * Dm;

static_assert(OFF_END <= 75497472ull, "d_out overlay overflow");
static_assert(OFF_P2E <= OFF_ENT, "phase2 overlay collides with ENT");

inline int cdiv(long a, long b) { return (int)((a + b - 1) / b); }

} // namespace

typedef short short4v __attribute__((ext_vector_type(4)));
typedef short short8v __attribute__((ext_vector_type(8)));
typedef float f32x4 __attribute__((ext_vector_type(4)));

__device__ __forceinline__ short f2bf(float f) {
  union { float f; uint32_t u; } v; v.f = f;
  uint32_t u = v.u;
  u += 0x7fffu + ((u >> 16) & 1u);   // round-to-nearest-even
  return (short)(u >> 16);
}

// ---------------------------------------------------------------------------
// small kernels (unchanged from round 1)
// ---------------------------------------------------------------------------

__global__ void k_count_type(const int* __restrict__ dst, const int* __restrict__ typ,
                             float* __restrict__ cnt, int E) {
  int i = blockIdx.x * 256 + threadIdx.x;
  if (i < E) atomicAdd(&cnt[(size_t)typ[i] * NE + dst[i]], 1.0f);
}

__global__ void k_deg(const int* __restrict__ dst, float* __restrict__ deg, int E) {
  int i = blockIdx.x * 256 + threadIdx.x;
  if (i < E) atomicAdd(&deg[dst[i]], 1.0f);
}

__global__ void k_dis(float* __restrict__ d, int n) {
  int i = blockIdx.x * 256 + threadIdx.x;
  if (i < n) d[i] = rsqrtf(d[i] + 1.0f);
}

__global__ void k_wcat(const float* __restrict__ comp, const float* __restrict__ bases,
                       float* __restrict__ Wc) {
  int idx = blockIdx.x * 256 + threadIdx.x;
  if (idx >= NREL * Dm * Dm) return;
  int r = idx / (Dm * Dm);
  int io = idx - r * (Dm * Dm);
  float s = 0.f;
#pragma unroll
  for (int b = 0; b < 8; ++b) s += comp[r * 8 + b] * bases[(size_t)b * Dm * Dm + io];
  Wc[idx] = s;
}

__global__ void k_scatter_rgcn(const int* __restrict__ ei, const int* __restrict__ typ,
                               const float* __restrict__ cnt, const float* __restrict__ x,
                               float* __restrict__ agg, int E, int r) {
  int w = (int)((blockIdx.x * (size_t)blockDim.x + threadIdx.x) >> 6);
  int lane = threadIdx.x & 63;
  if (w >= E) return;
  if (typ[w] != r) return;
  int s = ei[w], d = ei[E + w];
  float c = 1.0f / cnt[(size_t)r * NE + d];
  const float* xs = x + (size_t)s * Dm;
  float* od = agg + (size_t)d * Dm;
#pragma unroll
  for (int i = 0; i < Dm / 64; ++i)
    atomicAdd(&od[lane + 64 * i], c * xs[lane + 64 * i]);
}

__global__ void k_gcn_init(const float* __restrict__ x, const float* __restrict__ dis,
                           float* __restrict__ out, int n) {
  size_t i = (size_t)blockIdx.x * 256 + threadIdx.x;
  if (i >= (size_t)n * Dm) return;
  int row = (int)(i / Dm);
  float d = dis[row];
  out[i] = d * d * x[i];
}

__global__ void k_gcn_scatter(const int* __restrict__ ei, const float* __restrict__ dis,
                              const float* __restrict__ x, float* __restrict__ out, int E) {
  int w = (int)((blockIdx.x * (size_t)blockDim.x + threadIdx.x) >> 6);
  int lane = threadIdx.x & 63;
  if (w >= E) return;
  int s = ei[w], d = ei[E + w];
  float c = dis[s] * dis[d];
  const float* xs = x + (size_t)s * Dm;
  float* od = out + (size_t)d * Dm;
#pragma unroll
  for (int i = 0; i < Dm / 64; ++i)
    atomicAdd(&od[lane + 64 * i], c * xs[lane + 64 * i]);
}

__global__ void k_copy(float* __restrict__ d, const float* __restrict__ s, size_t n) {
  size_t i = (size_t)blockIdx.x * 256 + threadIdx.x;
  if (i < n) d[i] = s[i];
}

__global__ void k_addto(float* __restrict__ d, const float* __restrict__ s, size_t n) {
  size_t i = (size_t)blockIdx.x * 256 + threadIdx.x;
  if (i < n) d[i] += s[i];
}

__global__ void k_scale_from(float* __restrict__ d, const float* __restrict__ s,
                             float a, size_t n) {
  size_t i = (size_t)blockIdx.x * 256 + threadIdx.x;
  if (i < n) d[i] = a * s[i];
}

__global__ void k_gather(const int* __restrict__ idx, const float* __restrict__ x,
                         float* __restrict__ out, int rows, int D) {
  size_t i = (size_t)blockIdx.x * 256 + threadIdx.x;
  if (i >= (size_t)rows * D) return;
  int r = (int)(i / D);
  int d = (int)(i - (size_t)r * D);
  out[i] = x[(size_t)idx[r] * D + d];
}

__global__ void k_scatter_movie(const int* __restrict__ mte, const float* __restrict__ mm,
                                float* __restrict__ ent) {
  size_t i = (size_t)blockIdx.x * 256 + threadIdx.x;
  if (i >= MBF) return;
  int m = (int)(i / Dm);
  int d = (int)(i - (size_t)m * Dm);
  atomicAdd(&ent[(size_t)mte[m] * Dm + d], 0.25f * mm[i]);
}

// ---------------------------------------------------------------------------
// bf16 MFMA GEMM: C = act(A[M,K] @ W[K,N] + bias (+res)), or C += (ACCUM), or
// FINAL = write transposed prompt layout. f32 inputs converted to bf16 in
// staging. 128x128 tile, BK=64, 256 thr = 4 waves (2x2), each wave 64x64.
// LDS XOR-swizzle (slot ^= row&7 on 16B slots) -> conflict-free ds_read_b128.
// Requires K % 64 == 0, N % 8 == 0.
// ---------------------------------------------------------------------------
template <bool RELU, bool ACCUM, bool RES, bool FINAL>
__global__ __launch_bounds__(256) void mgemm(
    const float* __restrict__ A, const float* __restrict__ W,
    const float* __restrict__ bias, const float* __restrict__ Rp,
    float* __restrict__ C, int M, int N, int K) {
  __shared__ __align__(16) short As[128 * 64];
  __shared__ __align__(16) short Bs[128 * 64];
  const int tid = threadIdx.x;
  const int bm = blockIdx.x * 128, bn = blockIdx.y * 128;
  const int lane = tid & 63;
  const int w = tid >> 6;
  const int wr = (w >> 1) * 64, wc = (w & 1) * 64;
  const int lrow = lane & 15;
  const int lq = lane >> 4;

  f32x4 acc[4][4] = {};

  // A staging: thread -> (row, 32 contiguous k)
  const int s_row = tid >> 1;
  const int s_kh = (tid & 1) * 32;
  const bool a_ok = (bm + s_row) < M;
  const float* Ap = A + (size_t)(bm + s_row) * K + s_kh;
  // B staging: thread -> (4 k-rows, 8 n-cols)
  const int b_kq = tid >> 4;           // 0..15
  const int b_n0 = (tid & 15) * 8;
  const bool b_ok = (bn + b_n0) < N;   // N%8==0 -> all-or-nothing per chunk
  const float* Wp = W + (size_t)b_kq * 4 * N + bn + b_n0;

  for (int k0 = 0; k0 < K; k0 += 64) {
    float a_f[32];
    if (a_ok) {
      const float4* p = (const float4*)(Ap + k0);
#pragma unroll
      for (int i = 0; i < 8; ++i) {
        float4 v = p[i];
        a_f[i * 4 + 0] = v.x; a_f[i * 4 + 1] = v.y;
        a_f[i * 4 + 2] = v.z; a_f[i * 4 + 3] = v.w;
      }
    } else {
#pragma unroll
      for (int i = 0; i < 32; ++i) a_f[i] = 0.f;
    }
    float b_f[4][8];
    if (b_ok) {
#pragma unroll
      for (int kk = 0; kk < 4; ++kk) {
        const float4* p = (const float4*)(Wp + (size_t)(k0 + kk) * N);
        float4 v0 = p[0], v1 = p[1];
        b_f[kk][0] = v0.x; b_f[kk][1] = v0.y; b_f[kk][2] = v0.z; b_f[kk][3] = v0.w;
        b_f[kk][4] = v1.x; b_f[kk][5] = v1.y; b_f[kk][6] = v1.z; b_f[kk][7] = v1.w;
      }
    } else {
#pragma unroll
      for (int kk = 0; kk < 4; ++kk)
#pragma unroll
        for (int nn = 0; nn < 8; ++nn) b_f[kk][nn] = 0.f;
    }
    __syncthreads();   // previous tile's reads done
#pragma unroll
    for (int j = 0; j < 4; ++j) {
      short8v v;
#pragma unroll
      for (int e = 0; e < 8; ++e) v[e] = f2bf(a_f[j * 8 + e]);
      int kk = s_kh + j * 8;
      int off = s_row * 64 + (((kk >> 3) ^ (s_row & 7)) << 3);
      *(short8v*)&As[off] = v;
    }
#pragma unroll
    for (int nn = 0; nn < 8; ++nn) {
      short4v v;
#pragma unroll
      for (int kk = 0; kk < 4; ++kk) v[kk] = f2bf(b_f[kk][nn]);
      int r = b_n0 + nn;
      int off = r * 64 + (((b_kq >> 1) ^ (r & 7)) << 3) + (b_kq & 1) * 4;
      *(short4v*)&Bs[off] = v;
    }
    __syncthreads();
#pragma unroll
    for (int ks = 0; ks < 2; ++ks) {
      short8v af[4], bf[4];
      const int slot = ks * 4 + lq;
#pragma unroll
      for (int mr = 0; mr < 4; ++mr) {
        int r = wr + mr * 16 + lrow;
        af[mr] = *(const short8v*)&As[r * 64 + ((slot ^ (r & 7)) << 3)];
      }
#pragma unroll
      for (int nc = 0; nc < 4; ++nc) {
        int r = wc + nc * 16 + lrow;
        bf[nc] = *(const short8v*)&Bs[r * 64 + ((slot ^ (r & 7)) << 3)];
      }
#pragma unroll
      for (int mr = 0; mr < 4; ++mr)
#pragma unroll
        for (int nc = 0; nc < 4; ++nc)
          acc[mr][nc] = __builtin_amdgcn_mfma_f32_16x16x32_bf16(
              af[mr], bf[nc], acc[mr][nc], 0, 0, 0);
    }
  }
  // epilogue: D frag: col = lane&15, row = (lane>>4)*4 + e
#pragma unroll
  for (int mr = 0; mr < 4; ++mr) {
#pragma unroll
    for (int e = 0; e < 4; ++e) {
      int r = bm + wr + mr * 16 + lq * 4 + e;
      if (r >= M) continue;
#pragma unroll
      for (int nc = 0; nc < 4; ++nc) {
        int c = bn + wc + nc * 16 + lrow;
        if (c >= N) continue;
        float v = acc[mr][nc][e];
        if (bias) v += bias[c];
        if (RES) v += Rp[(size_t)r * N + c];
        if (RELU) v = fmaxf(v, 0.f);
        if (FINAL) {
          int b = r >> 8, t = r & 255;
          int l = c / 1536, rem = c - l * 1536;
          int blk = rem / 768, rem2 = rem - blk * 768;
          int hh = rem2 >> 6, dd = rem2 & 63;
          size_t oi = (((((size_t)l * 2 + blk) * 16 + b) * 12 + hh) * 256 + t) * 64 + dd;
          C[oi] = v;
        } else if (ACCUM) {
          C[(size_t)r * N + c] += v;
        } else {
          C[(size_t)r * N + c] = v;
        }
      }
    }
  }
}

// fused cross-attention: one wave per (b,t)  (unchanged)
__global__ __launch_bounds__(256) void k_attn(const float* __restrict__ q,
                                              const float* __restrict__ eemb,
                                              const float* __restrict__ tok,
                                              float* __restrict__ out) {
  int gw = (int)((blockIdx.x * (size_t)blockDim.x + threadIdx.x) >> 6);
  int lane = threadIdx.x & 63;
  if (gw >= NTOK) return;
  int b = gw >> 8;
  const float* qr = q + (size_t)gw * Hm;
  float qreg[12];
#pragma unroll
  for (int i = 0; i < 12; ++i) qreg[i] = qr[lane + 64 * i];
  const float* eb = eemb + (size_t)b * LE * Hm;
  float myA = -3.0e38f;
  for (int e = 0; e < LE; ++e) {
    const float* er = eb + (size_t)e * Hm;
    float s = 0.f;
#pragma unroll
    for (int i = 0; i < 12; ++i) s = fmaf(qreg[i], er[lane + 64 * i], s);
#pragma unroll
    for (int off = 32; off > 0; off >>= 1) s += __shfl_xor(s, off);
    if (lane == e) myA = s * (1.0f / 768.0f);
  }
  float mx = myA;
#pragma unroll
  for (int off = 32; off > 0; off >>= 1) mx = fmaxf(mx, __shfl_xor(mx, off));
  float p = (lane < LE) ? expf(myA - mx) : 0.f;
  float sum = p;
#pragma unroll
  for (int off = 32; off > 0; off >>= 1) sum += __shfl_xor(sum, off);
  float w = p / sum;
  const float* tr = tok + (size_t)gw * Hm;
  float acc[12];
#pragma unroll
  for (int i = 0; i < 12; ++i) acc[i] = tr[lane + 64 * i];
  for (int e = 0; e < LE; ++e) {
    float we = __shfl(w, e);
    const float* er = eb + (size_t)e * Hm;
#pragma unroll
    for (int i = 0; i < 12; ++i) acc[i] = fmaf(we, er[lane + 64 * i], acc[i]);
  }
  float* orow = out + (size_t)gw * Hm;
#pragma unroll
  for (int i = 0; i < 12; ++i) orow[lane + 64 * i] = acc[i];
}

// ---------------------------------------------------------------------------

extern "C" void kernel_launch(void* const* d_in, const int* in_sizes, int n_in,
                              void* d_out, int out_size, void* d_ws, size_t ws_size,
                              hipStream_t stream) {
  (void)in_sizes; (void)n_in; (void)out_size; (void)ws_size;

  const float* x_node = (const float*)d_in[0];
  const float* bases  = (const float*)d_in[1];
  const float* comp   = (const float*)d_in[2];
  const float* root   = (const float*)d_in[3];
  const float* rbias  = (const float*)d_in[4];
  const float* ep1w1  = (const float*)d_in[5];
  const float* ep1b1  = (const float*)d_in[6];
  const float* ep1w2  = (const float*)d_in[7];
  const float* ep1b2  = (const float*)d_in[8];
  const float* ep2w   = (const float*)d_in[9];
  const float* ep2b   = (const float*)d_in[10];
  const float* tp1w1  = (const float*)d_in[11];
  const float* tp1b1  = (const float*)d_in[12];
  const float* tp1w2  = (const float*)d_in[13];
  const float* tp1b2  = (const float*)d_in[14];
  const float* tp2w   = (const float*)d_in[15];
  const float* tp2b   = (const float*)d_in[16];
  const float* caw    = (const float*)d_in[17];
  const float* pp1w1  = (const float*)d_in[18];
  const float* pp1b1  = (const float*)d_in[19];
  const float* pp1w2  = (const float*)d_in[20];
  const float* pp1b2  = (const float*)d_in[21];
  const float* pp2w   = (const float*)d_in[22];
  const float* pp2b   = (const float*)d_in[23];
  const float* tokens = (const float*)d_in[24];
  const int* ei_kg = (const int*)d_in[25];
  const int* etype = (const int*)d_in[26];
  const int* ei_c  = (const int*)d_in[27];
  const int* ei_ts = (const int*)d_in[28];
  const int* ei_is = (const int*)d_in[29];
  const int* mte   = (const int*)d_in[30];
  const int* eids  = (const int*)d_in[31];

  float* O = (float*)d_out;
  float* f_agg  = O + OFF_AGG;
  float* f_ent0 = O + OFF_ENT0;
  float* f_acc  = O + OFF_ACC;
  float* f_ccur = O + OFF_CCUR;
  float* f_nf   = O + OFF_NF;
  float* f_g1   = O + OFF_G1;
  float* f_g2   = O + OFF_G2;
  float* f_mm   = O + OFF_MM;
  float* f_cnt  = O + OFF_CNT;
  float* f_wcat = O + OFF_WCAT;
  float* f_ent  = O + OFF_ENT;
  float* f_eemb = O + OFF_EEMB;
  float* f_disc = O + OFF_DISC;
  float* f_dist = O + OFF_DIST;
  float* f_disi = O + OFF_DISI;
  float* f_hid  = O + OFF_HID;
  float* f_ent2 = O + OFF_ENT2;
  float* f_e768 = O + OFF_E768;
  float* f_thid = O + OFF_THID;
  float* f_tok  = O + OFF_TOK;
  float* f_tok2 = O + OFF_TOK2;
  float* f_q    = O + OFF_Q;
  float* f_pr0  = O + OFF_PR0;
  float* f_phid = O + OFF_PHID;
  float* f_p2   = (float*)d_ws;

  const int EW = 256;

  // ---------------- RGCN ----------------
  hipMemsetAsync(f_cnt, 0, (size_t)NREL * NE * 4, stream);
  k_count_type<<<cdiv(EKG, EW), EW, 0, stream>>>(ei_kg + EKG, etype, f_cnt, EKG);
  k_wcat<<<cdiv(NREL * Dm * Dm, EW), EW, 0, stream>>>(comp, bases, f_wcat);
  mgemm<false, false, false, false><<<dim3(cdiv(NE, 128), cdiv(Dm, 128)), 256, 0, stream>>>(
      x_node, root, rbias, nullptr, f_ent0, NE, Dm, Dm);
  for (int r = 0; r < NREL; ++r) {
    hipMemsetAsync(f_agg, 0, NBf * 4, stream);
    k_scatter_rgcn<<<cdiv((long)EKG * 64, EW), EW, 0, stream>>>(
        ei_kg, etype, f_cnt, x_node, f_agg, EKG, r);
    mgemm<false, true, false, false><<<dim3(cdiv(NE, 128), cdiv(Dm, 128)), 256, 0, stream>>>(
        f_agg, f_wcat + (size_t)r * Dm * Dm, nullptr, nullptr, f_ent0, NE, Dm, Dm);
  }
  k_addto<<<cdiv(NBf, EW), EW, 0, stream>>>(f_ent0, x_node, NBf);

  // ---------------- degree norms ----------------
  hipMemsetAsync(f_disc, 0, NE * 4, stream);
  k_deg<<<cdiv(EC, EW), EW, 0, stream>>>(ei_c + EC, f_disc, EC);
  k_dis<<<cdiv(NE, EW), EW, 0, stream>>>(f_disc, NE);
  hipMemsetAsync(f_dist, 0, NM * 4, stream);
  k_deg<<<cdiv(ES, EW), EW, 0, stream>>>(ei_ts + ES, f_dist, ES);
  k_dis<<<cdiv(NM, EW), EW, 0, stream>>>(f_dist, NM);
  hipMemsetAsync(f_disi, 0, NM * 4, stream);
  k_deg<<<cdiv(ES, EW), EW, 0, stream>>>(ei_is + ES, f_disi, ES);
  k_dis<<<cdiv(NM, EW), EW, 0, stream>>>(f_disi, NM);

  // ---------------- movie branch ----------------
  k_gather<<<cdiv(MBF, EW), EW, 0, stream>>>(mte, f_ent0, f_nf, NM, Dm);
  hipMemsetAsync(f_mm, 0, MBF * 4, stream);
  k_gcn_init<<<cdiv(MBF, EW), EW, 0, stream>>>(f_nf, f_dist, f_g1, NM);
  k_gcn_scatter<<<cdiv((long)ES * 64, EW), EW, 0, stream>>>(ei_ts, f_dist, f_nf, f_g1, ES);
  k_addto<<<cdiv(MBF, EW), EW, 0, stream>>>(f_mm, f_g1, MBF);
  k_gcn_init<<<cdiv(MBF, EW), EW, 0, stream>>>(f_g1, f_dist, f_g2, NM);
  k_gcn_scatter<<<cdiv((long)ES * 64, EW), EW, 0, stream>>>(ei_ts, f_dist, f_g1, f_g2, ES);
  k_addto<<<cdiv(MBF, EW), EW, 0, stream>>>(f_mm, f_g2, MBF);
  k_gcn_init<<<cdiv(MBF, EW), EW, 0, stream>>>(f_nf, f_disi, f_g1, NM);
  k_gcn_scatter<<<cdiv((long)ES * 64, EW), EW, 0, stream>>>(ei_is, f_disi, f_nf, f_g1, ES);
  k_addto<<<cdiv(MBF, EW), EW, 0, stream>>>(f_mm, f_g1, MBF);
  k_gcn_init<<<cdiv(MBF, EW), EW, 0, stream>>>(f_g1, f_disi, f_g2, NM);
  k_gcn_scatter<<<cdiv((long)ES * 64, EW), EW, 0, stream>>>(ei_is, f_disi, f_g1, f_g2, ES);
  k_addto<<<cdiv(MBF, EW), EW, 0, stream>>>(f_mm, f_g2, MBF);

  // ---------------- entity GCN chain ----------------
  k_copy<<<cdiv(NBf, EW), EW, 0, stream>>>(f_acc, f_ent0, NBf);
  k_gcn_init<<<cdiv(NBf, EW), EW, 0, stream>>>(f_ent0, f_disc, f_agg, NE);
  k_gcn_scatter<<<cdiv((long)EC * 64, EW), EW, 0, stream>>>(ei_c, f_disc, f_ent0, f_agg, EC);
  k_addto<<<cdiv(NBf, EW), EW, 0, stream>>>(f_acc, f_agg, NBf);
  k_gcn_init<<<cdiv(NBf, EW), EW, 0, stream>>>(f_agg, f_disc, f_ccur, NE);
  k_gcn_scatter<<<cdiv((long)EC * 64, EW), EW, 0, stream>>>(ei_c, f_disc, f_agg, f_ccur, EC);
  k_addto<<<cdiv(NBf, EW), EW, 0, stream>>>(f_acc, f_ccur, NBf);
  k_gcn_init<<<cdiv(NBf, EW), EW, 0, stream>>>(f_ccur, f_disc, f_agg, NE);
  k_gcn_scatter<<<cdiv((long)EC * 64, EW), EW, 0, stream>>>(ei_c, f_disc, f_ccur, f_agg, EC);
  k_addto<<<cdiv(NBf, EW), EW, 0, stream>>>(f_acc, f_agg, NBf);
  k_scale_from<<<cdiv(NBf, EW), EW, 0, stream>>>(f_ent, f_acc, 0.25f, NBf);
  k_scatter_movie<<<cdiv(MBF, EW), EW, 0, stream>>>(mte, f_mm, f_ent);

  // ---------------- entity MLP ----------------
  mgemm<true, false, false, false><<<dim3(cdiv(NE, 128), cdiv(192, 128)), 256, 0, stream>>>(
      f_ent, ep1w1, ep1b1, nullptr, f_hid, NE, 192, Dm);
  mgemm<false, false, true, false><<<dim3(cdiv(NE, 128), cdiv(Dm, 128)), 256, 0, stream>>>(
      f_hid, ep1w2, ep1b2, f_ent, f_ent2, NE, Dm, 192);
  mgemm<false, false, false, false><<<dim3(cdiv(NE, 128), cdiv(Hm, 128)), 256, 0, stream>>>(
      f_ent2, ep2w, ep2b, nullptr, f_e768, NE, Hm, Dm);

  // ---------------- token path ----------------
  mgemm<true, false, false, false><<<dim3(cdiv(NTOK, 128), cdiv(Dm, 128)), 256, 0, stream>>>(
      tokens, tp1w1, tp1b1, nullptr, f_thid, NTOK, Dm, Hm);
  mgemm<false, false, true, false><<<dim3(cdiv(NTOK, 128), cdiv(Hm, 128)), 256, 0, stream>>>(
      f_thid, tp1w2, tp1b2, tokens, f_tok, NTOK, Hm, Dm);
  mgemm<false, false, false, false><<<dim3(cdiv(NTOK, 128), cdiv(Hm, 128)), 256, 0, stream>>>(
      f_tok, tp2w, tp2b, nullptr, f_tok2, NTOK, Hm, Hm);
  mgemm<false, false, false, false><<<dim3(cdiv(NTOK, 128), cdiv(Hm, 128)), 256, 0, stream>>>(
      f_tok2, caw, nullptr, nullptr, f_q, NTOK, Hm, Hm);

  k_gather<<<cdiv((long)Bc * LE * Hm, EW), EW, 0, stream>>>(eids, f_e768, f_eemb, Bc * LE, Hm);
  k_attn<<<cdiv((long)NTOK * 64, 256), 256, 0, stream>>>(f_q, f_eemb, f_tok2, f_pr0);

  mgemm<true, false, false, false><<<dim3(cdiv(NTOK, 128), cdiv(Dm, 128)), 256, 0, stream>>>(
      f_pr0, pp1w1, pp1b1, nullptr, f_phid, NTOK, Dm, Hm);
  mgemm<false, false, true, false><<<dim3(cdiv(NTOK, 128), cdiv(Hm, 128)), 256, 0, stream>>>(
      f_phid, pp1w2, pp1b2, f_pr0, f_p2, NTOK, Hm, Dm);

  // ---------------- final GEMM + transpose ----------------
  mgemm<false, false, false, true><<<dim3(cdiv(NTOK, 128), cdiv(NO, 128)), 256, 0, stream>>>(
      f_p2, pp2w, pp2b, nullptr, O, NTOK, NO, Hm);
}